// Round 2
// baseline (281.957 us; speedup 1.0000x reference)
//
#include <hip/hip_runtime.h>
#include <stdint.h>

typedef unsigned short u16;
typedef unsigned int   u32;
typedef __attribute__((ext_vector_type(8))) short short8;
typedef __attribute__((ext_vector_type(4))) float f32x4;

#define NTOK 4096
#define LOG2E 1.44269504088896340736f

// round-to-nearest-even f32 -> bf16
__device__ __forceinline__ u16 f2bf(float f) {
    u32 u = __builtin_bit_cast(u32, f);
    u += 0x7fffu + ((u >> 16) & 1u);
    return (u16)(u >> 16);
}
// pack two positive floats to bf16 pair (round-half-up; valid for exp2 outputs > 0)
__device__ __forceinline__ u32 pk_hu(float a, float b) {   // low half = a
    u32 ua = __builtin_bit_cast(u32, a) + 0x8000u;
    u32 ub = __builtin_bit_cast(u32, b) + 0x8000u;
    return (ua >> 16) | (ub & 0xffff0000u);
}

#define MFMA16x32 __builtin_amdgcn_mfma_f32_16x16x32_bf16

// ---------------- kernel 1: QKV projection via MFMA ----------------
// grid 512 = b(8) x slab(64 of 64 tokens); block 256 = 4 waves x 16 tokens.
// Stage x[b][:, n0..n0+63] -> LDS as X[tok][ch] bf16 (16B-slot XOR swizzle),
// weights read as B-frags straight from global (broadcast, L2-hot).
__global__ __launch_bounds__(256) void qkv_mfma(
    const float* __restrict__ x,
    const float* __restrict__ wq, const float* __restrict__ bq,
    const float* __restrict__ wk, const float* __restrict__ bk,
    const float* __restrict__ wv, const float* __restrict__ bv,
    u16* __restrict__ Q, u16* __restrict__ K, u16* __restrict__ Vt)
{
    __shared__ __align__(16) u16 Xl[64 * 64];   // row stride 64 u16 (128 B), slots swizzled
    const int tid = threadIdx.x;
    const int b   = blockIdx.x >> 6;
    const int n0  = (blockIdx.x & 63) << 6;
    const int g   = tid >> 6;        // wave id
    const int n   = tid & 63;        // lane = token within slab (staging)

    // ---- stage X^T -> X (transpose) ----
    float f0[8], f1[8];
#pragma unroll
    for (int p = 0; p < 8; ++p) {
        const int c0 = g * 16 + p * 2;
        f0[p] = x[(size_t)(b * 64 + c0) * NTOK + n0 + n];
        f1[p] = x[(size_t)(b * 64 + c0 + 1) * NTOK + n0 + n];
    }
#pragma unroll
    for (int p = 0; p < 8; ++p) {
        const int c0 = g * 16 + p * 2;
        const u32 pk = (u32)f2bf(f0[p]) | ((u32)f2bf(f1[p]) << 16);
        const int dw = ((c0 >> 3) ^ (n & 7)) * 4 + ((c0 >> 1) & 3);
        *(u32*)&Xl[n * 64 + dw * 2] = pk;
    }
    __syncthreads();

    const int wave = g;
    const int lane = tid & 63;
    const int quad = lane >> 4;
    const int l15  = lane & 15;
    const int row  = wave * 16 + l15;

    // A-frags: X[tok=row][ch = quad*8+j (+32k)]
    short8 xa[2];
#pragma unroll
    for (int k = 0; k < 2; ++k) {
        const int slot = (quad + 4 * k) ^ (row & 7);
        xa[k] = *(const short8*)&Xl[row * 64 + slot * 8];
    }

    u16* Qo = Q + (size_t)b * NTOK * 64;
    u16* Ko = K + (size_t)b * NTOK * 64;
    u16* Vo = Vt + (size_t)b * 64 * NTOK;
    const float QS = 0.125f * LOG2E;

    auto project = [&](const float* __restrict__ W, const float* __restrict__ bias,
                       float scale, u16* __restrict__ dst, bool transposed) {
#pragma unroll
        for (int nt = 0; nt < 4; ++nt) {
            const int d = nt * 16 + l15;
            const float* wr = W + (size_t)d * 64 + quad * 8;
            short8 wf0, wf1;
#pragma unroll
            for (int j = 0; j < 8; ++j) {
                wf0[j] = (short)f2bf(wr[j]);
                wf1[j] = (short)f2bf(wr[32 + j]);
            }
            f32x4 acc = {0.f, 0.f, 0.f, 0.f};
            acc = MFMA16x32(xa[0], wf0, acc, 0, 0, 0);
            acc = MFMA16x32(xa[1], wf1, acc, 0, 0, 0);
            const float bb = bias[d];
#pragma unroll
            for (int r = 0; r < 4; ++r) {
                const float v = (acc[r] + bb) * scale;
                const int rowt = wave * 16 + quad * 4 + r;     // token within slab
                if (!transposed) dst[(size_t)(n0 + rowt) * 64 + d] = f2bf(v);
                else             dst[(size_t)d * NTOK + n0 + rowt] = f2bf(v);
            }
        }
    };
    project(wq, bq, QS,  Qo, false);   // Q pre-scaled by 1/sqrt(C)*log2e for exp2 scores
    project(wk, bk, 1.f, Ko, false);
    project(wv, bv, 1.f, Vo, true);
}

// ---------------- kernel 2: fused attention + mix + 2x2 pool ----------------
// grid 256 = b(8) x oh(32); block 512 = 8 waves. Waves split over KV (512 tokens
// each); every wave holds ALL 128 Q-rows as B-frags (64 VGPR) and O accumulators
// (128 VGPR). S^T = K·Q^T so P packs as ds_write_b64. K/V frags load straight
// from global (each byte read once per wave, L2-resident). No __syncthreads in
// the K-loop. Epilogue: ds_add_f32 cross-wave O/l reduction into LDS aliasing
// the dead P region, then mix-MFMA + bias/relu + 2x2 avg pool.
__global__ __launch_bounds__(512, 2) void attn2(
    const u16* __restrict__ Q, const u16* __restrict__ K,
    const u16* __restrict__ Vt,
    const float* __restrict__ wm, const float* __restrict__ bm,
    float* __restrict__ out)
{
    __shared__ __align__(16) char smem[65536];   // 8 waves x P[128 rows][32 tok] bf16 (8 KB each)
    const int tid  = threadIdx.x;
    const int wave = tid >> 6;
    const int lane = tid & 63;
    const int quad = lane >> 4;
    const int l15  = lane & 15;
    const int b    = blockIdx.x >> 5;
    const int oh   = blockIdx.x & 31;
    const int n0   = oh * 128;

    // Q B-frags: B[k=ch][n=Qrow]: lane reads Q[row=16nt+l15][ch=8q.. (+32k)]
    const u16* qbase = Q + ((size_t)(b * NTOK + n0 + l15)) * 64 + quad * 8;
    short8 qf[8][2];
#pragma unroll
    for (int nt = 0; nt < 8; ++nt)
#pragma unroll
        for (int k = 0; k < 2; ++k)
            qf[nt][k] = *(const short8*)(qbase + nt * 1024 + k * 32);

    const u16* Kb = K + ((size_t)b * NTOK + wave * 512) * 64;
    const u16* Vb = Vt + (size_t)b * 64 * NTOK + wave * 512;
    u16* Pw = (u16*)(smem + wave * 8192);        // P[row][tok]: row stride 32 u16 (64 B)

    f32x4 O[8][4];
#pragma unroll
    for (int mt = 0; mt < 8; ++mt)
#pragma unroll
        for (int nt = 0; nt < 4; ++nt) O[mt][nt] = (f32x4){0.f, 0.f, 0.f, 0.f};
    float lp[8] = {0.f, 0.f, 0.f, 0.f, 0.f, 0.f, 0.f, 0.f};

#pragma unroll 1
    for (int t = 0; t < 16; ++t) {               // 16 tiles x 32 tokens = 512
        const u16* kt = Kb + t * 2048;
        short8 kf[2][2];
#pragma unroll
        for (int mt = 0; mt < 2; ++mt)
#pragma unroll
            for (int k = 0; k < 2; ++k)
                kf[mt][k] = *(const short8*)(kt + (mt * 16 + l15) * 64 + k * 32 + quad * 8);

        // S^T = K . Q^T ; D: col=l15=Qrow, row=4q+r = token (consecutive regs = consecutive tokens)
#pragma unroll
        for (int mt = 0; mt < 2; ++mt) {
#pragma unroll
            for (int nt = 0; nt < 8; ++nt) {
                f32x4 s = {0.f, 0.f, 0.f, 0.f};
                s = MFMA16x32(kf[mt][0], qf[nt][0], s, 0, 0, 0);
                s = MFMA16x32(kf[mt][1], qf[nt][1], s, 0, 0, 0);
                const float p0 = __builtin_amdgcn_exp2f(s[0]);
                const float p1 = __builtin_amdgcn_exp2f(s[1]);
                const float p2 = __builtin_amdgcn_exp2f(s[2]);
                const float p3 = __builtin_amdgcn_exp2f(s[3]);
                lp[nt] += (p0 + p1) + (p2 + p3);
                uint2 pk;
                pk.x = pk_hu(p0, p1);
                pk.y = pk_hu(p2, p3);
                *(uint2*)(Pw + (nt * 16 + l15) * 32 + mt * 16 + quad * 4) = pk;
            }
        }
        // V^T B-frags: lane reads Vt[ch=16nt+l15][tok=8q.. ]
        short8 vf[4];
#pragma unroll
        for (int nt = 0; nt < 4; ++nt)
            vf[nt] = *(const short8*)(Vb + (size_t)(nt * 16 + l15) * NTOK + t * 32 + quad * 8);
        // O += P . V  (A=P from LDS, same-wave in-order DS => no barrier)
#pragma unroll
        for (int mt = 0; mt < 8; ++mt) {
            const short8 pf = *(const short8*)(Pw + (mt * 16 + l15) * 32 + quad * 8);
#pragma unroll
            for (int nt = 0; nt < 4; ++nt)
                O[mt][nt] = MFMA16x32(pf, vf[nt], O[mt][nt], 0, 0, 0);
        }
    }

    // reduce lp over quads (quads hold disjoint tokens)
#pragma unroll
    for (int nt = 0; nt < 8; ++nt) {
        float s = lp[nt];
        s += __shfl_xor(s, 16);
        s += __shfl_xor(s, 32);
        lp[nt] = s;
    }

    __syncthreads();                              // all P reads done; alias region
    float* Obuf = (float*)smem;                   // [128][68] fp32 = 34816 B
    float* lbuf = (float*)(smem + 34816);         // [128] fp32
    // zero O/l region (35328 B = 8832 dwords)
#pragma unroll
    for (int i = 0; i < 18; ++i) {
        const int idx = tid + i * 512;
        if (idx < 8832) ((float*)smem)[idx] = 0.f;
    }
    __syncthreads();

    // cross-wave reduction
#pragma unroll
    for (int mt = 0; mt < 8; ++mt)
#pragma unroll
        for (int nt = 0; nt < 4; ++nt)
#pragma unroll
            for (int r = 0; r < 4; ++r)
                atomicAdd(&Obuf[(mt * 16 + quad * 4 + r) * 68 + nt * 16 + l15], O[mt][nt][r]);
    if (quad == 0) {
#pragma unroll
        for (int nt = 0; nt < 8; ++nt)
            atomicAdd(&lbuf[nt * 16 + l15], lp[nt]);
    }
    __syncthreads();

    // mix = relu(O_norm . wm^T + bm); wave w handles Q-rows [16w, 16w+16)
    const int arow = wave * 16 + l15;
    const float rinv = 1.0f / lbuf[arow];
    short8 af[2];
#pragma unroll
    for (int k = 0; k < 2; ++k) {
        const float* orow = &Obuf[arow * 68 + k * 32 + quad * 8];
#pragma unroll
        for (int j = 0; j < 4; ++j) {
            const float va = orow[2 * j] * rinv;
            const float vb = orow[2 * j + 1] * rinv;
            ((u32*)&af[k])[j] = (u32)f2bf(va) | ((u32)f2bf(vb) << 16);
        }
    }
    f32x4 mx[4];
#pragma unroll
    for (int nt = 0; nt < 4; ++nt) {
        const int d = nt * 16 + l15;
        const float* wr = wm + (size_t)d * 64 + quad * 8;
        short8 w0, w1;
#pragma unroll
        for (int j = 0; j < 8; ++j) {
            w0[j] = (short)f2bf(wr[j]);
            w1[j] = (short)f2bf(wr[32 + j]);
        }
        f32x4 acc = {0.f, 0.f, 0.f, 0.f};
        acc = MFMA16x32(af[0], w0, acc, 0, 0, 0);
        acc = MFMA16x32(af[1], w1, acc, 0, 0, 0);
        mx[nt] = acc;
    }
    // bias+relu, write M over Obuf (wave writes only its own 16 rows -> no barrier)
#pragma unroll
    for (int nt = 0; nt < 4; ++nt) {
        const float bb = bm[nt * 16 + l15];
#pragma unroll
        for (int r = 0; r < 4; ++r) {
            float v = mx[nt][r] + bb;
            v = v > 0.f ? v : 0.f;
            Obuf[(wave * 16 + quad * 4 + r) * 68 + nt * 16 + l15] = v;
        }
    }
    __syncthreads();

    // 2x2 avg pool (bilinear 2x downsample, half-pixel): rows 0..63 = image row 2oh, 64..127 = 2oh+1
    const int ow = tid & 31;
    const int cb = (tid >> 5) & 15;
#pragma unroll
    for (int i = 0; i < 4; ++i) {
        const int c = cb + i * 16;
        const float v = 0.25f * (Obuf[(2 * ow) * 68 + c] + Obuf[(2 * ow + 1) * 68 + c]
                               + Obuf[(64 + 2 * ow) * 68 + c] + Obuf[(65 + 2 * ow) * 68 + c]);
        out[((size_t)(b * 64 + c) * 32 + oh) * 32 + ow] = v;
    }
}

extern "C" void kernel_launch(void* const* d_in, const int* in_sizes, int n_in,
                              void* d_out, int out_size, void* d_ws, size_t ws_size,
                              hipStream_t stream) {
    (void)in_sizes; (void)n_in; (void)out_size; (void)ws_size;
    const float* x  = (const float*)d_in[0];
    const float* wq = (const float*)d_in[1];
    const float* bq = (const float*)d_in[2];
    const float* wk = (const float*)d_in[3];
    const float* bk = (const float*)d_in[4];
    const float* wv = (const float*)d_in[5];
    const float* bv = (const float*)d_in[6];
    const float* wm = (const float*)d_in[7];
    const float* bm = (const float*)d_in[8];

    // workspace: Q bf16 [8][4096][64] | K bf16 [8][4096][64] | Vt bf16 [8][64][4096] = 12 MB
    u16* Q  = (u16*)d_ws;
    u16* K  = Q + (size_t)8 * NTOK * 64;
    u16* Vt = K + (size_t)8 * NTOK * 64;

    qkv_mfma<<<512, 256, 0, stream>>>(x, wq, bq, wk, bk, wv, bv, Q, K, Vt);
    attn2<<<256, 512, 0, stream>>>(Q, K, Vt, wm, bm, (float*)d_out);
}